// Round 5
// baseline (942.569 us; speedup 1.0000x reference)
//
#include <hip/hip_runtime.h>
#include <cstdint>
#include <cstddef>

#define B_ 8
#define C_ 512
#define T_ 8192

typedef unsigned short ushort_t;
typedef __attribute__((ext_vector_type(8))) short short8;            // 8 bf16 = 4 VGPR (MFMA A/B frag)
typedef __attribute__((ext_vector_type(8))) unsigned short ushort8_t;
typedef __attribute__((ext_vector_type(4))) float floatx4;           // MFMA C/D frag
typedef __attribute__((ext_vector_type(4))) unsigned int uintx4;

__device__ __forceinline__ ushort_t f2bf(float f) {
    // round-to-nearest-even fp32 -> bf16 (finite inputs)
    unsigned int u = __float_as_uint(f);
    u += 0x7FFFu + ((u >> 16) & 1u);
    return (ushort_t)(u >> 16);
}

// ---------------------------------------------------------------------------
// Fused Activation1d producing TRANSPOSED bf16 output z_T[b][t][c].
// (unchanged — verified)
// ---------------------------------------------------------------------------
#define CT   32     // channels per block
#define TT   128    // t per block
#define XSTR 148    // LDS x row stride (floats)
#define ZSTR 40     // z stage row stride (halves)

__global__ __launch_bounds__(256) void act_t_kernel(
    const float* __restrict__ X,   // [B][C][T] fp32
    const float* __restrict__ la, const float* __restrict__ lb,
    const float* __restrict__ fu, const float* __restrict__ fd,
    ushort_t* __restrict__ Zt)     // [B][T][C] bf16
{
    __shared__ __align__(16) float    xl[CT * XSTR];   // 18944 B
    __shared__ __align__(16) ushort_t zs[TT * ZSTR];   // 10240 B

    const int t0  = blockIdx.x * TT;
    const int c0  = blockIdx.y * CT;
    const int b   = blockIdx.z;
    const int tid = threadIdx.x;

    const bool interior = (t0 >= 8) && (t0 + 136 <= T_);

    // ---- stage x rows [c0..c0+31] x global t in [t0-8, t0+136) ----
    {
        const int row = tid >> 3;          // 0..31
        const int js  = tid & 7;           // 8 threads per row
        const float* Xr = X + ((size_t)b * C_ + c0 + row) * T_;
        if (interior) {
            const float* src = Xr + (t0 - 8);   // 16B-aligned (t0 % 128 == 0)
#pragma unroll
            for (int k = 0; k < 5; ++k) {
                const int seg = js + k * 8;
                if (seg < 36)
                    *(floatx4*)&xl[row * XSTR + seg * 4] = *(const floatx4*)&src[seg * 4];
            }
        } else {
#pragma unroll
            for (int e = 0; e < 18; ++e) {
                const int i = js * 18 + e;
                int t = t0 - 8 + i;
                t = min(max(t, 0), T_ - 1);
                xl[row * XSTR + i] = Xr[t];
            }
        }
    }

    float f[12], g[12];
#pragma unroll
    for (int j = 0; j < 12; ++j) { f[j] = fu[j]; g[j] = fd[j]; }

    const int cl   = tid & 31;
    const int st   = tid >> 5;       // 0..7
    const int st16 = st * 16;
    const int c    = c0 + cl;
    const float alpha = __expf(la[c]);
    const float invb  = 1.0f / (__expf(lb[c]) + 1e-9f);

    __syncthreads();

    float zacc[16];
#pragma unroll
    for (int i = 0; i < 16; ++i) zacc[i] = 0.f;

    if (interior) {
        float xw[32];
#pragma unroll
        for (int i = 0; i < 8; ++i)
            *(floatx4*)&xw[i * 4] = *(const floatx4*)&xl[cl * XSTR + st16 + i * 4];

#pragma unroll
        for (int m = 0; m < 42; ++m) {
            const int h = m >> 1;
            float y = 0.f;
            if (m & 1) {
#pragma unroll
                for (int q = 0; q < 6; ++q) y += xw[3 + h + q] * f[11 - 2 * q];
            } else {
#pragma unroll
                for (int q = 0; q < 6; ++q) y += xw[3 + h + q] * f[10 - 2 * q];
            }
            y *= 2.f;
            const float sn = __sinf(y * alpha);
            y += invb * sn * sn;
            const int dlo = (m >= 11) ? ((m - 10) >> 1) : 0;
            const int dhi = (h < 15) ? h : 15;
#pragma unroll
            for (int dt = dlo; dt <= dhi; ++dt)
                zacc[dt] += g[m - 2 * dt] * y;
        }
    } else {
        const int ts = t0 + st16;
        const float* xr = &xl[cl * XSTR];
#pragma unroll
        for (int m = 0; m < 42; ++m) {
            const int h = m >> 1;
            int n = 2 * ts - 5 + m;
            n = min(max(n, 0), 2 * T_ - 1);
            const int u    = n >> 1;
            const int base = u - (t0 - 8);
            float y = 0.f;
            if (n & 1) {
#pragma unroll
                for (int q = 0; q < 6; ++q) y += xr[base - 2 + q] * f[10 - 2 * q];
            } else {
#pragma unroll
                for (int q = 0; q < 6; ++q) y += xr[base - 3 + q] * f[11 - 2 * q];
            }
            y *= 2.f;
            const float sn = __sinf(y * alpha);
            y += invb * sn * sn;
            const int dlo = (m >= 11) ? ((m - 10) >> 1) : 0;
            const int dhi = (h < 15) ? h : 15;
#pragma unroll
            for (int dt = dlo; dt <= dhi; ++dt)
                zacc[dt] += g[m - 2 * dt] * y;
        }
    }

#pragma unroll
    for (int r = 0; r < 16; ++r)
        zs[(st16 + r) * ZSTR + cl] = f2bf(zacc[r]);

    __syncthreads();

    const int seg = tid & 3;
    const int rr  = tid >> 2;     // 0..63
#pragma unroll
    for (int p = 0; p < 2; ++p) {
        const int row = p * 64 + rr;
        *(uintx4*)&Zt[((size_t)b * T_ + t0 + row) * C_ + c0 + seg * 8] =
            *(const uintx4*)&zs[row * ZSTR + seg * 8];
    }
}

// ---------------------------------------------------------------------------
// Pack W [o][c][k] fp32 -> MFMA-fragment-ordered bf16 (unchanged):
// Wb[(k*16+cc)*32 + ot][lane][j] = W[ot*16+(lane&15)][cc*32+(lane>>4)*8+j][k]
// ---------------------------------------------------------------------------
__global__ __launch_bounds__(256) void pack_w_kernel(
    const float* __restrict__ W, ushort_t* __restrict__ Wb)
{
    const int gid   = blockIdx.x * 256 + threadIdx.x;   // 0..98303
    const int lane  = gid & 63;
    const int rest  = gid >> 6;          // k*512 + chunk*32 + ot
    const int ot    = rest & 31;
    const int chunk = (rest >> 5) & 15;
    const int k     = rest >> 9;
    const int o     = ot * 16 + (lane & 15);
    const int c0    = chunk * 32 + (lane >> 4) * 8;
    ushort8_t v;
#pragma unroll
    for (int j = 0; j < 8; ++j)
        v[j] = f2bf(W[((size_t)o * C_ + c0 + j) * 3 + k]);
    *(ushort8_t*)&Wb[(size_t)gid * 8] = v;
}

// ---------------------------------------------------------------------------
// Conv1d C->C K=3 zero-pad as 3 shifted bf16 MFMA GEMMs, fp32 accumulate.
// v5: B-fragments load DIRECTLY global->VGPR (the 16x16x32 B-frag layout is
//     lane-natural in Zt[t][c]: 16 t-rows x 64B, coalesced per row) in a
//     3-register software pipeline one k-step ahead — no B LDS at all.
//     A stays gll->LDS double-buffered (L2-resident Wb, linear, conflict-lite).
//     LDS 48KB -> 3 blocks/CU (launch_bounds(256,3)).
//     XCD-aware bijective swizzle: logical = b*256 + t*4 + o, so each XCD owns
//     one batch and the 4 o-tiles sharing a B panel are co-resident -> B loads
//     are L2 hits and Zt is fetched once.
// Block tile 128(o) x 128(t); 4 waves each 64x64 via 16x16x32_bf16.
// ---------------------------------------------------------------------------
#define ABUF 12288   // halves per A buffer (24 segs * 512)

__global__ __launch_bounds__(256, 3) void conv_mfma_kernel(
    const ushort_t* __restrict__ Zt,   // [B][T][C] bf16
    const ushort_t* __restrict__ Wb,   // frag-packed weights
    const float* __restrict__ bias,
    const float* __restrict__ resid,
    float* __restrict__ Out,           // [B][C][T] fp32
    const int addResid)
{
    __shared__ __align__(16) ushort_t Al[2 * ABUF];   // 49,152 B

    // ---- XCD-aware swizzle: hw id -> logical (b, tIdx, oIdx). 2048 % 8 == 0.
    const int hid = blockIdx.x;                 // grid = 2048 linear
    const int L   = (hid & 7) * 256 + (hid >> 3);
    const int b   = L >> 8;                     // 0..7
    const int rem = L & 255;
    const int t0  = (rem >> 2) * 128;
    const int o0  = (rem & 3) * 128;

    const int tid = threadIdx.x;
    const int lane = tid & 63;
    const int w    = tid >> 6;
    const int wo   = w & 1;        // o half
    const int wt   = w >> 1;       // t half

    const ushort_t* zb = Zt + (size_t)b * T_ * C_;

    floatx4 acc[4][4];
#pragma unroll
    for (int i = 0; i < 4; ++i)
#pragma unroll
        for (int j = 0; j < 4; ++j)
            acc[i][j] = (floatx4){0.f, 0.f, 0.f, 0.f};

    const int aoff = wo * 2048 + lane * 8;   // A read base (halves)

    // ---- B direct-load geometry: frag (k,j) lane l reads 16B at
    //      Zt[t0-1 + wt*64 + j*16 + (l&15) + k][ch*32 + (l>>4)*8]
    const int  tB   = t0 - 1 + wt * 64 + (lane & 15);
    const int  cB   = (lane >> 4) * 8;
    const bool edge = (t0 == 0) || (t0 == T_ - 128);
    const ushort_t* bbase = zb + (size_t)(edge ? 0 : tB) * C_ + cB;

    auto stageA = [&](ushort_t* abuf, int ch) {
#pragma unroll
        for (int s = 0; s < 6; ++s) {
            const int seg = w * 6 + s;
            const int k   = seg >> 3;
            const int ot8 = seg & 7;
            const ushort_t* src =
                Wb + (size_t)(((k * 16 + ch) * 32) + (o0 >> 4) + ot8) * 512 + lane * 8;
            __builtin_amdgcn_global_load_lds(
                (const __attribute__((address_space(1))) unsigned int*)src,
                (__attribute__((address_space(3))) unsigned int*)(abuf + seg * 512),
                16, 0, 0);
        }
    };

    auto loadB = [&](short8 bf[4], int ch, int k) {
        if (!edge) {
#pragma unroll
            for (int j = 0; j < 4; ++j)
                bf[j] = *(const short8*)(bbase + (size_t)(ch * 32 + k * 512 + j * 8192));
        } else {
            const short8 zv = {0, 0, 0, 0, 0, 0, 0, 0};
#pragma unroll
            for (int j = 0; j < 4; ++j) {
                const int t  = tB + j * 16 + k;
                const int tc = min(max(t, 0), T_ - 1);
                short8 v = *(const short8*)&zb[(size_t)tc * C_ + ch * 32 + cB];
                bf[j] = (t == tc) ? v : zv;
            }
        }
    };

    auto mm16 = [&](short8 af[4], short8 bf[4]) {
#pragma unroll
        for (int i = 0; i < 4; ++i)
#pragma unroll
            for (int j = 0; j < 4; ++j)
                acc[i][j] = __builtin_amdgcn_mfma_f32_16x16x32_bf16(
                    af[i], bf[j], acc[i][j], 0, 0, 0);
    };

    short8 r0[4], r1[4], r2[4], af[4];

    // ---- prologue
    stageA(Al, 0);
    loadB(r0, 0, 0);
    loadB(r1, 0, 1);
    __syncthreads();

    for (int ch = 0; ch < 16; ++ch) {
        const ushort_t* curA = Al + (ch & 1) * ABUF;
        ushort_t* nxtA = Al + ((ch + 1) & 1) * ABUF;

        loadB(r2, ch, 2);                       // ~2 MFMA-bursts of lead
        if (ch < 15) stageA(nxtA, ch + 1);      // L2-resident, drained at barrier

        // k = 0
#pragma unroll
        for (int i = 0; i < 4; ++i)
            af[i] = *(const short8*)&curA[aoff + i * 512];
        mm16(af, r0);
        if (ch < 15) loadB(r0, ch + 1, 0);

        // k = 1
#pragma unroll
        for (int i = 0; i < 4; ++i)
            af[i] = *(const short8*)&curA[aoff + (8 + i) * 512];
        mm16(af, r1);
        if (ch < 15) loadB(r1, ch + 1, 1);

        // k = 2
#pragma unroll
        for (int i = 0; i < 4; ++i)
            af[i] = *(const short8*)&curA[aoff + (16 + i) * 512];
        mm16(af, r2);

        if (ch < 15) __syncthreads();           // A dbuf swap
    }

    // --- epilogue: D[row=o][col=t], row=(lane>>4)*4+reg, col=lane&15
    const int tc0 = t0 + wt * 64 + (lane & 15);
#pragma unroll
    for (int i = 0; i < 4; ++i) {
        const int ob = o0 + wo * 64 + i * 16 + (lane >> 4) * 4;
#pragma unroll
        for (int r = 0; r < 4; ++r) {
            const int o = ob + r;
            const float bs = bias[o];
            const size_t rowoff = ((size_t)b * C_ + o) * T_;
#pragma unroll
            for (int j = 0; j < 4; ++j) {
                const int t = tc0 + j * 16;
                float v = acc[i][j][r] + bs;
                if (addResid) v += resid[rowoff + t];
                Out[rowoff + t] = v;
            }
        }
    }
}

extern "C" void kernel_launch(void* const* d_in, const int* in_sizes, int n_in,
                              void* d_out, int out_size, void* d_ws, size_t ws_size,
                              hipStream_t stream)
{
    const float* x   = (const float*)d_in[0];
    const float* a1a = (const float*)d_in[1];
    const float* a1b = (const float*)d_in[2];
    const float* a2a = (const float*)d_in[3];
    const float* a2b = (const float*)d_in[4];
    const float* c1w = (const float*)d_in[5];
    const float* c1b = (const float*)d_in[6];
    const float* c2w = (const float*)d_in[7];
    const float* c2b = (const float*)d_in[8];
    const float* fu  = (const float*)d_in[9];
    const float* fd  = (const float*)d_in[10];
    float* out = (float*)d_out;

    // workspace layout
    ushort_t* Zt  = (ushort_t*)d_ws;                                   // 67,108,864 B
    float*    y1  = (float*)((char*)d_ws + 67108864);                  // 134,217,728 B
    ushort_t* Wb1 = (ushort_t*)((char*)d_ws + 67108864 + 134217728);   // 1,572,864 B
    ushort_t* Wb2 = Wb1 + 786432;                                      // 1,572,864 B

    dim3 agrid(T_ / TT, C_ / CT, B_);

    pack_w_kernel<<<384, 256, 0, stream>>>(c1w, Wb1);
    pack_w_kernel<<<384, 256, 0, stream>>>(c2w, Wb2);

    // xt = act1(x) -> z_T bf16
    act_t_kernel<<<agrid, 256, 0, stream>>>(x, a1a, a1b, fu, fd, Zt);
    // xt = conv1(xt) -> y1 fp32
    conv_mfma_kernel<<<2048, 256, 0, stream>>>(Zt, Wb1, c1b, x, y1, 0);
    // xt = act2(xt) -> z_T bf16
    act_t_kernel<<<agrid, 256, 0, stream>>>(y1, a2a, a2b, fu, fd, Zt);
    // out = conv2(xt) + x
    conv_mfma_kernel<<<2048, 256, 0, stream>>>(Zt, Wb2, c2b, x, out, 1);
}

// Round 6
// 927.050 us; speedup vs baseline: 1.0167x; 1.0167x over previous
//
#include <hip/hip_runtime.h>
#include <cstdint>
#include <cstddef>

#define B_ 8
#define C_ 512
#define T_ 8192

typedef unsigned short ushort_t;
typedef __attribute__((ext_vector_type(8))) short short8;            // 8 bf16 = 4 VGPR (MFMA A/B frag)
typedef __attribute__((ext_vector_type(8))) unsigned short ushort8_t;
typedef __attribute__((ext_vector_type(4))) float floatx4;           // MFMA C/D frag
typedef __attribute__((ext_vector_type(4))) unsigned int uintx4;

__device__ __forceinline__ ushort_t f2bf(float f) {
    // round-to-nearest-even fp32 -> bf16 (finite inputs)
    unsigned int u = __float_as_uint(f);
    u += 0x7FFFu + ((u >> 16) & 1u);
    return (ushort_t)(u >> 16);
}

// ---------------------------------------------------------------------------
// Fused Activation1d producing TRANSPOSED bf16 output z_T[b][t][c].
// (unchanged — verified)
// ---------------------------------------------------------------------------
#define CT   32     // channels per block
#define TT   128    // t per block
#define XSTR 148    // LDS x row stride (floats)
#define ZSTR 40     // z stage row stride (halves)

__global__ __launch_bounds__(256) void act_t_kernel(
    const float* __restrict__ X,   // [B][C][T] fp32
    const float* __restrict__ la, const float* __restrict__ lb,
    const float* __restrict__ fu, const float* __restrict__ fd,
    ushort_t* __restrict__ Zt)     // [B][T][C] bf16
{
    __shared__ __align__(16) float    xl[CT * XSTR];   // 18944 B
    __shared__ __align__(16) ushort_t zs[TT * ZSTR];   // 10240 B

    const int t0  = blockIdx.x * TT;
    const int c0  = blockIdx.y * CT;
    const int b   = blockIdx.z;
    const int tid = threadIdx.x;

    const bool interior = (t0 >= 8) && (t0 + 136 <= T_);

    // ---- stage x rows [c0..c0+31] x global t in [t0-8, t0+136) ----
    {
        const int row = tid >> 3;          // 0..31
        const int js  = tid & 7;           // 8 threads per row
        const float* Xr = X + ((size_t)b * C_ + c0 + row) * T_;
        if (interior) {
            const float* src = Xr + (t0 - 8);   // 16B-aligned (t0 % 128 == 0)
#pragma unroll
            for (int k = 0; k < 5; ++k) {
                const int seg = js + k * 8;
                if (seg < 36)
                    *(floatx4*)&xl[row * XSTR + seg * 4] = *(const floatx4*)&src[seg * 4];
            }
        } else {
#pragma unroll
            for (int e = 0; e < 18; ++e) {
                const int i = js * 18 + e;
                int t = t0 - 8 + i;
                t = min(max(t, 0), T_ - 1);
                xl[row * XSTR + i] = Xr[t];
            }
        }
    }

    float f[12], g[12];
#pragma unroll
    for (int j = 0; j < 12; ++j) { f[j] = fu[j]; g[j] = fd[j]; }

    const int cl   = tid & 31;
    const int st   = tid >> 5;       // 0..7
    const int st16 = st * 16;
    const int c    = c0 + cl;
    const float alpha = __expf(la[c]);
    const float invb  = 1.0f / (__expf(lb[c]) + 1e-9f);

    __syncthreads();

    float zacc[16];
#pragma unroll
    for (int i = 0; i < 16; ++i) zacc[i] = 0.f;

    if (interior) {
        float xw[32];
#pragma unroll
        for (int i = 0; i < 8; ++i)
            *(floatx4*)&xw[i * 4] = *(const floatx4*)&xl[cl * XSTR + st16 + i * 4];

#pragma unroll
        for (int m = 0; m < 42; ++m) {
            const int h = m >> 1;
            float y = 0.f;
            if (m & 1) {
#pragma unroll
                for (int q = 0; q < 6; ++q) y += xw[3 + h + q] * f[11 - 2 * q];
            } else {
#pragma unroll
                for (int q = 0; q < 6; ++q) y += xw[3 + h + q] * f[10 - 2 * q];
            }
            y *= 2.f;
            const float sn = __sinf(y * alpha);
            y += invb * sn * sn;
            const int dlo = (m >= 11) ? ((m - 10) >> 1) : 0;
            const int dhi = (h < 15) ? h : 15;
#pragma unroll
            for (int dt = dlo; dt <= dhi; ++dt)
                zacc[dt] += g[m - 2 * dt] * y;
        }
    } else {
        const int ts = t0 + st16;
        const float* xr = &xl[cl * XSTR];
#pragma unroll
        for (int m = 0; m < 42; ++m) {
            const int h = m >> 1;
            int n = 2 * ts - 5 + m;
            n = min(max(n, 0), 2 * T_ - 1);
            const int u    = n >> 1;
            const int base = u - (t0 - 8);
            float y = 0.f;
            if (n & 1) {
#pragma unroll
                for (int q = 0; q < 6; ++q) y += xr[base - 2 + q] * f[10 - 2 * q];
            } else {
#pragma unroll
                for (int q = 0; q < 6; ++q) y += xr[base - 3 + q] * f[11 - 2 * q];
            }
            y *= 2.f;
            const float sn = __sinf(y * alpha);
            y += invb * sn * sn;
            const int dlo = (m >= 11) ? ((m - 10) >> 1) : 0;
            const int dhi = (h < 15) ? h : 15;
#pragma unroll
            for (int dt = dlo; dt <= dhi; ++dt)
                zacc[dt] += g[m - 2 * dt] * y;
        }
    }

#pragma unroll
    for (int r = 0; r < 16; ++r)
        zs[(st16 + r) * ZSTR + cl] = f2bf(zacc[r]);

    __syncthreads();

    const int seg = tid & 3;
    const int rr  = tid >> 2;     // 0..63
#pragma unroll
    for (int p = 0; p < 2; ++p) {
        const int row = p * 64 + rr;
        *(uintx4*)&Zt[((size_t)b * T_ + t0 + row) * C_ + c0 + seg * 8] =
            *(const uintx4*)&zs[row * ZSTR + seg * 8];
    }
}

// ---------------------------------------------------------------------------
// Pack W [o][c][k] fp32 -> MFMA-fragment-ordered bf16 (unchanged):
// Wb[(k*16+cc)*32 + ot][lane][j] = W[ot*16+(lane&15)][cc*32+(lane>>4)*8+j][k]
// ---------------------------------------------------------------------------
__global__ __launch_bounds__(256) void pack_w_kernel(
    const float* __restrict__ W, ushort_t* __restrict__ Wb)
{
    const int gid   = blockIdx.x * 256 + threadIdx.x;   // 0..98303
    const int lane  = gid & 63;
    const int rest  = gid >> 6;          // k*512 + chunk*32 + ot
    const int ot    = rest & 31;
    const int chunk = (rest >> 5) & 15;
    const int k     = rest >> 9;
    const int o     = ot * 16 + (lane & 15);
    const int c0    = chunk * 32 + (lane >> 4) * 8;
    ushort8_t v;
#pragma unroll
    for (int j = 0; j < 8; ++j)
        v[j] = f2bf(W[((size_t)o * C_ + c0 + j) * 3 + k]);
    *(ushort8_t*)&Wb[(size_t)gid * 8] = v;
}

// ---------------------------------------------------------------------------
// Conv1d C->C K=3 zero-pad as 3 shifted bf16 MFMA GEMMs, fp32 accumulate.
// v6: v5 data paths (B direct global->VGPR in 3-reg rotation; A gll->LDS dbuf;
//     XCD swizzle) + T3/T4 counted-vmcnt RAW barrier:
//       [stageA(ch+1) 6 glls][SB0][3x: ds_read af; 16 MFMA; reload rX<-ch+1]
//       [SB0][s_waitcnt vmcnt(12)][SB0][s_barrier]
//     vmcnt(12) retires the A-glls only; the 12 B-reloads stay in flight
//     ACROSS the barrier (consumed next iter via compiler waits). Nothing
//     drains to 0 in the loop. sched_barrier(0) pins program order so the
//     count is exact (B loads cannot hoist above the glls).
// LDS 48KB -> 3 blocks/CU, 12 waves/CU.
// Block tile 128(o) x 128(t); 4 waves each 64x64 via 16x16x32_bf16.
// ---------------------------------------------------------------------------
#define ABUF 12288   // halves per A buffer (24 segs * 512)

__global__ __launch_bounds__(256, 3) void conv_mfma_kernel(
    const ushort_t* __restrict__ Zt,   // [B][T][C] bf16
    const ushort_t* __restrict__ Wb,   // frag-packed weights
    const float* __restrict__ bias,
    const float* __restrict__ resid,
    float* __restrict__ Out,           // [B][C][T] fp32
    const int addResid)
{
    __shared__ __align__(16) ushort_t Al[2 * ABUF];   // 49,152 B

    // ---- XCD-aware swizzle: hw id -> logical (b, tIdx, oIdx). 2048 % 8 == 0.
    const int hid = blockIdx.x;                 // grid = 2048 linear
    const int L   = (hid & 7) * 256 + (hid >> 3);
    const int b   = L >> 8;                     // 0..7
    const int rem = L & 255;
    const int t0  = (rem >> 2) * 128;
    const int o0  = (rem & 3) * 128;

    const int tid = threadIdx.x;
    const int lane = tid & 63;
    const int w    = tid >> 6;
    const int wo   = w & 1;        // o half
    const int wt   = w >> 1;       // t half

    const ushort_t* zb = Zt + (size_t)b * T_ * C_;

    floatx4 acc[4][4];
#pragma unroll
    for (int i = 0; i < 4; ++i)
#pragma unroll
        for (int j = 0; j < 4; ++j)
            acc[i][j] = (floatx4){0.f, 0.f, 0.f, 0.f};

    const int aoff = wo * 2048 + lane * 8;   // A read base (halves)

    // ---- B direct-load geometry: frag (k,j) lane l reads 16B at
    //      Zt[t0-1 + wt*64 + j*16 + (l&15) + k][ch*32 + (l>>4)*8]
    const int  tB   = t0 - 1 + wt * 64 + (lane & 15);
    const int  cB   = (lane >> 4) * 8;
    const bool edge = (t0 == 0) || (t0 == T_ - 128);
    const ushort_t* bbase = zb + (size_t)(edge ? 0 : tB) * C_ + cB;

    auto stageA = [&](ushort_t* abuf, int ch) {
#pragma unroll
        for (int s = 0; s < 6; ++s) {
            const int seg = w * 6 + s;
            const int k   = seg >> 3;
            const int ot8 = seg & 7;
            const ushort_t* src =
                Wb + (size_t)(((k * 16 + ch) * 32) + (o0 >> 4) + ot8) * 512 + lane * 8;
            __builtin_amdgcn_global_load_lds(
                (const __attribute__((address_space(1))) unsigned int*)src,
                (__attribute__((address_space(3))) unsigned int*)(abuf + seg * 512),
                16, 0, 0);
        }
    };

    auto loadB = [&](short8 bf[4], int ch, int k) {
        if (!edge) {
#pragma unroll
            for (int j = 0; j < 4; ++j)
                bf[j] = *(const short8*)(bbase + (size_t)(ch * 32 + k * 512 + j * 8192));
        } else {
            const short8 zv = {0, 0, 0, 0, 0, 0, 0, 0};
#pragma unroll
            for (int j = 0; j < 4; ++j) {
                const int t  = tB + j * 16 + k;
                const int tc = min(max(t, 0), T_ - 1);
                short8 v = *(const short8*)&zb[(size_t)tc * C_ + ch * 32 + cB];
                bf[j] = (t == tc) ? v : zv;
            }
        }
    };

    auto mm16 = [&](short8 af[4], short8 bf[4]) {
#pragma unroll
        for (int i = 0; i < 4; ++i)
#pragma unroll
            for (int j = 0; j < 4; ++j)
                acc[i][j] = __builtin_amdgcn_mfma_f32_16x16x32_bf16(
                    af[i], bf[j], acc[i][j], 0, 0, 0);
    };

    short8 r0[4], r1[4], r2[4], af[4];

    // ---- prologue: stage A(0), prefetch B(0) k=0..2, counted wait + raw barrier
    stageA(Al, 0);
    __builtin_amdgcn_sched_barrier(0);
    loadB(r0, 0, 0);
    loadB(r1, 0, 1);
    loadB(r2, 0, 2);
    __builtin_amdgcn_sched_barrier(0);
    asm volatile("s_waitcnt vmcnt(12)" ::: "memory");   // A(0) glls landed; B(0) in flight
    __builtin_amdgcn_sched_barrier(0);
    __builtin_amdgcn_s_barrier();

    for (int ch = 0; ch < 16; ++ch) {
        const ushort_t* curA = Al + (ch & 1) * ABUF;
        ushort_t* nxtA = Al + ((ch + 1) & 1) * ABUF;

        if (ch < 15) stageA(nxtA, ch + 1);
        __builtin_amdgcn_sched_barrier(0);   // pin: B reloads below stay below glls

        // k = 0
#pragma unroll
        for (int i = 0; i < 4; ++i)
            af[i] = *(const short8*)&curA[aoff + i * 512];
        mm16(af, r0);
        if (ch < 15) loadB(r0, ch + 1, 0);

        // k = 1
#pragma unroll
        for (int i = 0; i < 4; ++i)
            af[i] = *(const short8*)&curA[aoff + (8 + i) * 512];
        mm16(af, r1);
        if (ch < 15) loadB(r1, ch + 1, 1);

        // k = 2
#pragma unroll
        for (int i = 0; i < 4; ++i)
            af[i] = *(const short8*)&curA[aoff + (16 + i) * 512];
        mm16(af, r2);
        if (ch < 15) loadB(r2, ch + 1, 2);

        if (ch < 15) {
            __builtin_amdgcn_sched_barrier(0);
            // retire this iter's 6 A-glls (12 B reloads stay in flight)
            asm volatile("s_waitcnt vmcnt(12)" ::: "memory");
            __builtin_amdgcn_sched_barrier(0);
            __builtin_amdgcn_s_barrier();
        }
    }

    // --- epilogue: D[row=o][col=t], row=(lane>>4)*4+reg, col=lane&15
    const int tc0 = t0 + wt * 64 + (lane & 15);
#pragma unroll
    for (int i = 0; i < 4; ++i) {
        const int ob = o0 + wo * 64 + i * 16 + (lane >> 4) * 4;
#pragma unroll
        for (int r = 0; r < 4; ++r) {
            const int o = ob + r;
            const float bs = bias[o];
            const size_t rowoff = ((size_t)b * C_ + o) * T_;
#pragma unroll
            for (int j = 0; j < 4; ++j) {
                const int t = tc0 + j * 16;
                float v = acc[i][j][r] + bs;
                if (addResid) v += resid[rowoff + t];
                Out[rowoff + t] = v;
            }
        }
    }
}

extern "C" void kernel_launch(void* const* d_in, const int* in_sizes, int n_in,
                              void* d_out, int out_size, void* d_ws, size_t ws_size,
                              hipStream_t stream)
{
    const float* x   = (const float*)d_in[0];
    const float* a1a = (const float*)d_in[1];
    const float* a1b = (const float*)d_in[2];
    const float* a2a = (const float*)d_in[3];
    const float* a2b = (const float*)d_in[4];
    const float* c1w = (const float*)d_in[5];
    const float* c1b = (const float*)d_in[6];
    const float* c2w = (const float*)d_in[7];
    const float* c2b = (const float*)d_in[8];
    const float* fu  = (const float*)d_in[9];
    const float* fd  = (const float*)d_in[10];
    float* out = (float*)d_out;

    // workspace layout
    ushort_t* Zt  = (ushort_t*)d_ws;                                   // 67,108,864 B
    float*    y1  = (float*)((char*)d_ws + 67108864);                  // 134,217,728 B
    ushort_t* Wb1 = (ushort_t*)((char*)d_ws + 67108864 + 134217728);   // 1,572,864 B
    ushort_t* Wb2 = Wb1 + 786432;                                      // 1,572,864 B

    dim3 agrid(T_ / TT, C_ / CT, B_);

    pack_w_kernel<<<384, 256, 0, stream>>>(c1w, Wb1);
    pack_w_kernel<<<384, 256, 0, stream>>>(c2w, Wb2);

    // xt = act1(x) -> z_T bf16
    act_t_kernel<<<agrid, 256, 0, stream>>>(x, a1a, a1b, fu, fd, Zt);
    // xt = conv1(xt) -> y1 fp32
    conv_mfma_kernel<<<2048, 256, 0, stream>>>(Zt, Wb1, c1b, x, y1, 0);
    // xt = act2(xt) -> z_T bf16
    act_t_kernel<<<agrid, 256, 0, stream>>>(y1, a2a, a2b, fu, fd, Zt);
    // out = conv2(xt) + x
    conv_mfma_kernel<<<2048, 256, 0, stream>>>(Zt, Wb2, c2b, x, out, 1);
}

// Round 7
// 744.901 us; speedup vs baseline: 1.2654x; 1.2445x over previous
//
#include <hip/hip_runtime.h>
#include <cstdint>
#include <cstddef>

#define B_ 8
#define C_ 512
#define T_ 8192

typedef unsigned short ushort_t;
typedef __attribute__((ext_vector_type(8))) short short8;            // 8 bf16 = 4 VGPR (MFMA A/B frag)
typedef __attribute__((ext_vector_type(8))) unsigned short ushort8_t;
typedef __attribute__((ext_vector_type(4))) float floatx4;           // MFMA C/D frag
typedef __attribute__((ext_vector_type(4))) unsigned int uintx4;

__device__ __forceinline__ ushort_t f2bf(float f) {
    // round-to-nearest-even fp32 -> bf16 (finite inputs)
    unsigned int u = __float_as_uint(f);
    u += 0x7FFFu + ((u >> 16) & 1u);
    return (ushort_t)(u >> 16);
}

// ---------------------------------------------------------------------------
// Fused Activation1d producing TRANSPOSED bf16 output z_T[b][t][c].
// v7: identical structure to v2 (verified) with the ×2 folded into the
//     up-filter registers at load (f[j] = 2*fu[j]) — removes 42 v_mul/thread.
// ---------------------------------------------------------------------------
#define CT   32     // channels per block
#define TT   128    // t per block
#define XSTR 148    // LDS x row stride (floats)
#define ZSTR 40     // z stage row stride (halves)

__global__ __launch_bounds__(256) void act_t_kernel(
    const float* __restrict__ X,   // [B][C][T] fp32
    const float* __restrict__ la, const float* __restrict__ lb,
    const float* __restrict__ fu, const float* __restrict__ fd,
    ushort_t* __restrict__ Zt)     // [B][T][C] bf16
{
    __shared__ __align__(16) float    xl[CT * XSTR];   // 18944 B
    __shared__ __align__(16) ushort_t zs[TT * ZSTR];   // 10240 B

    const int t0  = blockIdx.x * TT;
    const int c0  = blockIdx.y * CT;
    const int b   = blockIdx.z;
    const int tid = threadIdx.x;

    const bool interior = (t0 >= 8) && (t0 + 136 <= T_);

    // ---- stage x rows [c0..c0+31] x global t in [t0-8, t0+136) ----
    {
        const int row = tid >> 3;          // 0..31
        const int js  = tid & 7;           // 8 threads per row
        const float* Xr = X + ((size_t)b * C_ + c0 + row) * T_;
        if (interior) {
            const float* src = Xr + (t0 - 8);   // 16B-aligned (t0 % 128 == 0)
#pragma unroll
            for (int k = 0; k < 5; ++k) {
                const int seg = js + k * 8;
                if (seg < 36)
                    *(floatx4*)&xl[row * XSTR + seg * 4] = *(const floatx4*)&src[seg * 4];
            }
        } else {
#pragma unroll
            for (int e = 0; e < 18; ++e) {
                const int i = js * 18 + e;
                int t = t0 - 8 + i;
                t = min(max(t, 0), T_ - 1);
                xl[row * XSTR + i] = Xr[t];
            }
        }
    }

    float f[12], g[12];
#pragma unroll
    for (int j = 0; j < 12; ++j) { f[j] = 2.0f * fu[j]; g[j] = fd[j]; }

    const int cl   = tid & 31;
    const int st   = tid >> 5;       // 0..7
    const int st16 = st * 16;
    const int c    = c0 + cl;
    const float alpha = __expf(la[c]);
    const float invb  = 1.0f / (__expf(lb[c]) + 1e-9f);

    __syncthreads();

    float zacc[16];
#pragma unroll
    for (int i = 0; i < 16; ++i) zacc[i] = 0.f;

    if (interior) {
        float xw[32];
#pragma unroll
        for (int i = 0; i < 8; ++i)
            *(floatx4*)&xw[i * 4] = *(const floatx4*)&xl[cl * XSTR + st16 + i * 4];

#pragma unroll
        for (int m = 0; m < 42; ++m) {
            const int h = m >> 1;
            float y = 0.f;
            if (m & 1) {
#pragma unroll
                for (int q = 0; q < 6; ++q) y += xw[3 + h + q] * f[11 - 2 * q];
            } else {
#pragma unroll
                for (int q = 0; q < 6; ++q) y += xw[3 + h + q] * f[10 - 2 * q];
            }
            const float sn = __sinf(y * alpha);
            y += invb * sn * sn;
            const int dlo = (m >= 11) ? ((m - 10) >> 1) : 0;
            const int dhi = (h < 15) ? h : 15;
#pragma unroll
            for (int dt = dlo; dt <= dhi; ++dt)
                zacc[dt] += g[m - 2 * dt] * y;
        }
    } else {
        const int ts = t0 + st16;
        const float* xr = &xl[cl * XSTR];
#pragma unroll
        for (int m = 0; m < 42; ++m) {
            const int h = m >> 1;
            int n = 2 * ts - 5 + m;
            n = min(max(n, 0), 2 * T_ - 1);
            const int u    = n >> 1;
            const int base = u - (t0 - 8);
            float y = 0.f;
            if (n & 1) {
#pragma unroll
                for (int q = 0; q < 6; ++q) y += xr[base - 2 + q] * f[10 - 2 * q];
            } else {
#pragma unroll
                for (int q = 0; q < 6; ++q) y += xr[base - 3 + q] * f[11 - 2 * q];
            }
            const float sn = __sinf(y * alpha);
            y += invb * sn * sn;
            const int dlo = (m >= 11) ? ((m - 10) >> 1) : 0;
            const int dhi = (h < 15) ? h : 15;
#pragma unroll
            for (int dt = dlo; dt <= dhi; ++dt)
                zacc[dt] += g[m - 2 * dt] * y;
        }
    }

#pragma unroll
    for (int r = 0; r < 16; ++r)
        zs[(st16 + r) * ZSTR + cl] = f2bf(zacc[r]);

    __syncthreads();

    const int seg = tid & 3;
    const int rr  = tid >> 2;     // 0..63
#pragma unroll
    for (int p = 0; p < 2; ++p) {
        const int row = p * 64 + rr;
        *(uintx4*)&Zt[((size_t)b * T_ + t0 + row) * C_ + c0 + seg * 8] =
            *(const uintx4*)&zs[row * ZSTR + seg * 8];
    }
}

// ---------------------------------------------------------------------------
// Pack W [o][c][k] fp32 -> MFMA-fragment-ordered bf16 (unchanged):
// Wb[(k*16+cc)*32 + ot][lane][j] = W[ot*16+(lane&15)][cc*32+(lane>>4)*8+j][k]
// ---------------------------------------------------------------------------
__global__ __launch_bounds__(256) void pack_w_kernel(
    const float* __restrict__ W, ushort_t* __restrict__ Wb)
{
    const int gid   = blockIdx.x * 256 + threadIdx.x;   // 0..98303
    const int lane  = gid & 63;
    const int rest  = gid >> 6;          // k*512 + chunk*32 + ot
    const int ot    = rest & 31;
    const int chunk = (rest >> 5) & 15;
    const int k     = rest >> 9;
    const int o     = ot * 16 + (lane & 15);
    const int c0    = chunk * 32 + (lane >> 4) * 8;
    ushort8_t v;
#pragma unroll
    for (int j = 0; j < 8; ++j)
        v[j] = f2bf(W[((size_t)o * C_ + c0 + j) * 3 + k]);
    *(ushort8_t*)&Wb[(size_t)gid * 8] = v;
}

// ---------------------------------------------------------------------------
// Conv1d C->C K=3 zero-pad as 3 shifted bf16 MFMA GEMMs, fp32 accumulate.
// v7 conv = EXACT v4 inner structure (best verified: 244 µs) + XCD-aware
//     bijective block swizzle (only change: blockIdx mapping; o-fastest so
//     the 4 o-tiles sharing a B panel are L2-co-resident).
// A via global_load_lds dbuf; B paired-row swizzled LDS dbuf; one barrier
// per c32 chunk. Block tile 128(o) x 128(t); 4 waves each 64x64.
// LDS = 2*24KB (A) + 2*8.25KB (B) = 64.5KB -> 2 blocks/CU.
// ---------------------------------------------------------------------------
#define ABUF 12288   // halves per A buffer (24 segs * 512)
#define BBUF 4224    // halves per B buffer (66 LDS rows * 64)

__global__ __launch_bounds__(256, 2) void conv_mfma_kernel(
    const ushort_t* __restrict__ Zt,   // [B][T][C] bf16
    const ushort_t* __restrict__ Wb,   // frag-packed weights
    const float* __restrict__ bias,
    const float* __restrict__ resid,
    float* __restrict__ Out,           // [B][C][T] fp32
    const int addResid)
{
    __shared__ __align__(16) ushort_t Al[2 * ABUF];   // 49,152 B
    __shared__ __align__(16) ushort_t Bs[2 * BBUF];   // 16,896 B

    // ---- XCD-aware swizzle: hw id -> logical (b, tIdx, oIdx). 2048 % 8 == 0.
    const int hid = blockIdx.x;                 // grid = 2048 linear
    const int L   = (hid & 7) * 256 + (hid >> 3);
    const int b   = L >> 8;                     // 0..7
    const int rem = L & 255;
    const int t0  = (rem >> 2) * 128;
    const int o0  = (rem & 3) * 128;

    const int tid = threadIdx.x;
    const int lane = tid & 63;
    const int w    = tid >> 6;
    const int wo   = w & 1;        // o half
    const int wt   = w >> 1;       // t half

    const ushort_t* zb = Zt + (size_t)b * T_ * C_;

    floatx4 acc[4][4];
#pragma unroll
    for (int i = 0; i < 4; ++i)
#pragma unroll
        for (int j = 0; j < 4; ++j)
            acc[i][j] = (floatx4){0.f, 0.f, 0.f, 0.f};

    // ---- B read offsets (halves), chunk-invariant.
    // t-row rr (t = t0-1+rr) lives at LDS row pr=(rr+1)>>1, sub-row e=(rr+1)&1;
    // 16B seg q at slot ((e<<2)|q) ^ (pr&7).
    int bofs[3][4];
#pragma unroll
    for (int k = 0; k < 3; ++k)
#pragma unroll
        for (int j = 0; j < 4; ++j) {
            const int rr = wt * 64 + j * 16 + (lane & 15) + k;
            const int pr = (rr + 1) >> 1;
            const int slot = ((((rr + 1) & 1) << 2) | (lane >> 4)) ^ (pr & 7);
            bofs[k][j] = pr * 64 + slot * 8;
        }

    const int aoff = wo * 2048 + lane * 8;   // A read base (halves)

    // ---- B main-stage source precompute (inverse swizzle), G-invariant parts.
    const int prw = 1 + (lane >> 3);
    const int ub  = (lane & 7) ^ (prw & 7);
    const int tb0 = t0 + 2 * prw - 2 + (ub >> 2);   // + 16*G
    const int cb0 = (ub & 3) * 8;                   // + chunk*32

    // ---- edge t-rows (rr=0: t0-1, rr=129: t0+128) via reg path, 8 threads
    const bool eth = (tid < 8);
    const int  eq  = tid & 3;
    const int  ehi = (tid >> 2) & 1;
    const int  t_e = ehi ? (t0 + 128) : (t0 - 1);
    const bool evv = eth && (t_e >= 0) && (t_e < T_);
    const int  edst = ehi ? (65 * 64 + (eq ^ 1) * 8)   // rr=129: pr=65,e=0
                          : ((4 + eq) * 8);            // rr=0:   pr=0, e=1
    const ushort_t* esrc0 = zb + (size_t)t_e * C_ + eq * 8;   // + chunk*32

    auto stageA = [&](ushort_t* abuf, int ch) {
#pragma unroll
        for (int s = 0; s < 6; ++s) {
            const int seg = w * 6 + s;
            const int k   = seg >> 3;
            const int ot8 = seg & 7;
            const ushort_t* src =
                Wb + (size_t)(((k * 16 + ch) * 32) + (o0 >> 4) + ot8) * 512 + lane * 8;
            __builtin_amdgcn_global_load_lds(
                (const __attribute__((address_space(1))) unsigned int*)src,
                (__attribute__((address_space(3))) unsigned int*)(abuf + seg * 512),
                16, 0, 0);
        }
    };
    auto stageB = [&](ushort_t* bbuf, int ch) {
#pragma unroll
        for (int gi = 0; gi < 2; ++gi) {
            const int G = w * 2 + gi;
            const ushort_t* src = zb + (size_t)(tb0 + 16 * G) * C_ + ch * 32 + cb0;
            __builtin_amdgcn_global_load_lds(
                (const __attribute__((address_space(1))) unsigned int*)src,
                (__attribute__((address_space(3))) unsigned int*)(bbuf + (1 + 8 * G) * 64),
                16, 0, 0);
        }
    };

    // ---- prologue: stage chunk 0
    stageA(Al, 0);
    stageB(Bs, 0);
    {
        uintx4 ev = (uintx4){0u, 0u, 0u, 0u};
        if (evv) ev = *(const uintx4*)esrc0;
        if (eth) *(uintx4*)&Bs[edst] = ev;
    }
    __syncthreads();

#pragma unroll 2
    for (int ch = 0; ch < 16; ++ch) {
        ushort_t* curA = Al + (ch & 1) * ABUF;
        ushort_t* curB = Bs + (ch & 1) * BBUF;
        ushort_t* nxtA = Al + ((ch + 1) & 1) * ABUF;
        ushort_t* nxtB = Bs + ((ch + 1) & 1) * BBUF;

        uintx4 ev = (uintx4){0u, 0u, 0u, 0u};
        if (ch < 15) {
            stageA(nxtA, ch + 1);
            stageB(nxtB, ch + 1);
            if (evv) ev = *(const uintx4*)(esrc0 + (ch + 1) * 32);
        }

#pragma unroll
        for (int k = 0; k < 3; ++k) {
            short8 af[4], bf[4];
#pragma unroll
            for (int i = 0; i < 4; ++i)
                af[i] = *(const short8*)&curA[aoff + (k * 8 + i) * 512];
#pragma unroll
            for (int j = 0; j < 4; ++j)
                bf[j] = *(const short8*)&curB[bofs[k][j]];
#pragma unroll
            for (int i = 0; i < 4; ++i)
#pragma unroll
                for (int j = 0; j < 4; ++j)
                    acc[i][j] = __builtin_amdgcn_mfma_f32_16x16x32_bf16(
                        af[i], bf[j], acc[i][j], 0, 0, 0);
        }

        if (ch < 15) {
            if (eth) *(uintx4*)&nxtB[edst] = ev;
            __syncthreads();
        }
    }

    // --- epilogue: D[row=o][col=t], row=(lane>>4)*4+reg, col=lane&15
    const int tc0 = t0 + wt * 64 + (lane & 15);
#pragma unroll
    for (int i = 0; i < 4; ++i) {
        const int ob = o0 + wo * 64 + i * 16 + (lane >> 4) * 4;
#pragma unroll
        for (int r = 0; r < 4; ++r) {
            const int o = ob + r;
            const float bs = bias[o];
            const size_t rowoff = ((size_t)b * C_ + o) * T_;
#pragma unroll
            for (int j = 0; j < 4; ++j) {
                const int t = tc0 + j * 16;
                float v = acc[i][j][r] + bs;
                if (addResid) v += resid[rowoff + t];
                Out[rowoff + t] = v;
            }
        }
    }
}

extern "C" void kernel_launch(void* const* d_in, const int* in_sizes, int n_in,
                              void* d_out, int out_size, void* d_ws, size_t ws_size,
                              hipStream_t stream)
{
    const float* x   = (const float*)d_in[0];
    const float* a1a = (const float*)d_in[1];
    const float* a1b = (const float*)d_in[2];
    const float* a2a = (const float*)d_in[3];
    const float* a2b = (const float*)d_in[4];
    const float* c1w = (const float*)d_in[5];
    const float* c1b = (const float*)d_in[6];
    const float* c2w = (const float*)d_in[7];
    const float* c2b = (const float*)d_in[8];
    const float* fu  = (const float*)d_in[9];
    const float* fd  = (const float*)d_in[10];
    float* out = (float*)d_out;

    // workspace layout
    ushort_t* Zt  = (ushort_t*)d_ws;                                   // 67,108,864 B
    float*    y1  = (float*)((char*)d_ws + 67108864);                  // 134,217,728 B
    ushort_t* Wb1 = (ushort_t*)((char*)d_ws + 67108864 + 134217728);   // 1,572,864 B
    ushort_t* Wb2 = Wb1 + 786432;                                      // 1,572,864 B

    dim3 agrid(T_ / TT, C_ / CT, B_);

    pack_w_kernel<<<384, 256, 0, stream>>>(c1w, Wb1);
    pack_w_kernel<<<384, 256, 0, stream>>>(c2w, Wb2);

    // xt = act1(x) -> z_T bf16
    act_t_kernel<<<agrid, 256, 0, stream>>>(x, a1a, a1b, fu, fd, Zt);
    // xt = conv1(xt) -> y1 fp32
    conv_mfma_kernel<<<2048, 256, 0, stream>>>(Zt, Wb1, c1b, x, y1, 0);
    // xt = act2(xt) -> z_T bf16
    act_t_kernel<<<agrid, 256, 0, stream>>>(y1, a2a, a2b, fu, fd, Zt);
    // out = conv2(xt) + x
    conv_mfma_kernel<<<2048, 256, 0, stream>>>(Zt, Wb2, c2b, x, out, 1);
}